// Round 1
// baseline (1542.380 us; speedup 1.0000x reference)
//
#include <hip/hip_runtime.h>
#include <hip/hip_bf16.h>
#include <cstdint>

// MupCausalSelfAttention on MI355X (gfx950), bf16 MFMA pipeline.
// B=4, T=2048, C=2048, H=16, Dh=128. muP scale = 1/Dh = 1/128.
//
// ws layout (bf16 elems):
//   qkv  : [8192][6144]                 50,331,648 elems
//   vT   : [64 bh][128 d][2048 t]       16,777,216
//   xb/y : [8192][2048] (y overlays xb) 16,777,216
//   wqT  : [6144][2048]                 12,582,912
//   woT  : [2048][2048]                  4,194,304
//   total 100,663,296 elems = 201,326,592 bytes of d_ws.

using f32x4  = __attribute__((ext_vector_type(4))) float;
using u32x4  = __attribute__((ext_vector_type(4))) unsigned int;
using u16x8  = __attribute__((ext_vector_type(8))) unsigned short;
using u16x4  = __attribute__((ext_vector_type(4))) unsigned short;
using bf16x8 = __attribute__((ext_vector_type(8))) __bf16;

__device__ __forceinline__ unsigned short f2bf(float f) {
  unsigned int u = __builtin_bit_cast(unsigned int, f);
  u += 0x7fffu + ((u >> 16) & 1u);   // round-to-nearest-even
  return (unsigned short)(u >> 16);
}

// ---------------- cast x fp32 -> bf16, 8 elems/thread ----------------
__global__ __launch_bounds__(256) void cast_x_kernel(const float* __restrict__ x,
                                                     unsigned short* __restrict__ xb) {
  const size_t i = (size_t)blockIdx.x * 256 + threadIdx.x;
  const float* p = x + i * 8;
  f32x4 a = *(const f32x4*)p;
  f32x4 b = *(const f32x4*)(p + 4);
  u16x8 o;
#pragma unroll
  for (int e = 0; e < 4; ++e) { o[e] = f2bf(a[e]); o[e + 4] = f2bf(b[e]); }
  *(u32x4*)(xb + i * 8) = __builtin_bit_cast(u32x4, o);
}

// ---------- W[K][N] fp32 -> WT[N][K] bf16, 64x64 LDS tile ----------
__global__ __launch_bounds__(256) void transpose_cast_w(const float* __restrict__ W,
                                                        unsigned short* __restrict__ WT,
                                                        int K, int N) {
  __shared__ unsigned short tbuf[64 * 68];
  const int tid = threadIdx.x;
  const int k0 = blockIdx.x * 64, n0 = blockIdx.y * 64;
#pragma unroll
  for (int it = 0; it < 4; ++it) {
    int c = it * 256 + tid;
    int kl = c >> 4, n4 = (c & 15) * 4;
    f32x4 v = *(const f32x4*)(W + (size_t)(k0 + kl) * N + n0 + n4);
#pragma unroll
    for (int e = 0; e < 4; ++e) tbuf[(n4 + e) * 68 + kl] = f2bf(v[e]);
  }
  __syncthreads();
#pragma unroll
  for (int it = 0; it < 2; ++it) {
    int c = it * 256 + tid;
    int nl = c >> 3, k8 = (c & 7) * 8;
    u16x4 lo = *(const u16x4*)&tbuf[nl * 68 + k8];
    u16x4 hi = *(const u16x4*)&tbuf[nl * 68 + k8 + 4];
    u16x8 o;
#pragma unroll
    for (int e = 0; e < 4; ++e) { o[e] = lo[e]; o[e + 4] = hi[e]; }
    *(u32x4*)(WT + (size_t)(n0 + nl) * K + k0 + k8) = __builtin_bit_cast(u32x4, o);
  }
}

// ---- qkv V-slice -> vT[bh][128 d][2048 t] bf16, 64x64 LDS tile ----
__global__ __launch_bounds__(256) void transpose_v_kernel(const unsigned short* __restrict__ qkv,
                                                          unsigned short* __restrict__ vT) {
  __shared__ unsigned short tbuf[64 * 68];
  const int tid = threadIdx.x;
  const int t0 = blockIdx.x * 64;
  const int d0 = blockIdx.y * 64;
  const int bh = blockIdx.z;
  const int b = bh >> 4, h = bh & 15;
#pragma unroll
  for (int it = 0; it < 2; ++it) {
    int c = it * 256 + tid;
    int tl = c >> 3, d8 = (c & 7) * 8;
    u32x4 v = *(const u32x4*)(qkv + (size_t)(b * 2048 + t0 + tl) * 6144 + 4096 + h * 128 + d0 + d8);
    u16x8 u = __builtin_bit_cast(u16x8, v);
#pragma unroll
    for (int e = 0; e < 8; ++e) tbuf[(d8 + e) * 68 + tl] = u[e];
  }
  __syncthreads();
#pragma unroll
  for (int it = 0; it < 2; ++it) {
    int c = it * 256 + tid;
    int dl = c >> 3, t8 = (c & 7) * 8;
    u16x4 lo = *(const u16x4*)&tbuf[dl * 68 + t8];
    u16x4 hi = *(const u16x4*)&tbuf[dl * 68 + t8 + 4];
    u16x8 o;
#pragma unroll
    for (int e = 0; e < 4; ++e) { o[e] = lo[e]; o[e + 4] = hi[e]; }
    *(u32x4*)(vT + ((size_t)bh * 128 + d0 + dl) * 2048 + t0 + t8) = __builtin_bit_cast(u32x4, o);
  }
}

// ------- C[M,N] = A[M,K] @ BT[N,K]^T + bias, bf16 MFMA 16x16x32 -------
// 128x128 tile, BK=32, 4 waves each 64x64 (4x4 MFMA tiles).
// A-frag: A[m=lane&15][k=quad*8+j]; B-frag: B^T row n=lane&15, k=quad*8+j.
// C/D layout: col=lane&15, row=quad*4+reg (m89/m91-verified).
template <bool OUT_BF16>
__global__ __launch_bounds__(256) void gemm_bt(const unsigned short* __restrict__ A,
                                               const unsigned short* __restrict__ BT,
                                               const float* __restrict__ bias,
                                               void* __restrict__ Cout,
                                               int M, int N, int K) {
  constexpr int LDT = 40;  // 32 + 8 pad: b128 frag reads stay ~2-way (free) on banks
  __shared__ unsigned short As[128 * LDT];
  __shared__ unsigned short Bs[128 * LDT];
  const int tid  = threadIdx.x;
  const int lane = tid & 63;
  const int wave = tid >> 6;
  const int wm = (wave >> 1) * 64;
  const int wn = (wave & 1) * 64;
  const int m0 = blockIdx.x * 128;
  const int n0 = blockIdx.y * 128;
  const int r16  = lane & 15;
  const int quad = lane >> 4;
  const int sr = tid >> 2;         // staging row (0..63), +64 on second half
  const int sc = (tid & 3) * 8;    // staging col (8 bf16 = 16B chunks)

  f32x4 acc[4][4] = {};
  const unsigned short* Aptr = A + (size_t)(m0 + sr) * K + sc;
  const unsigned short* Bptr = BT + (size_t)(n0 + sr) * K + sc;

  for (int k0 = 0; k0 < K; k0 += 32) {
#pragma unroll
    for (int half = 0; half < 2; ++half) {
      u32x4 va = *(const u32x4*)(Aptr + (size_t)half * 64 * K + k0);
      u32x4 vb = *(const u32x4*)(Bptr + (size_t)half * 64 * K + k0);
      *(u32x4*)(As + (sr + half * 64) * LDT + sc) = va;
      *(u32x4*)(Bs + (sr + half * 64) * LDT + sc) = vb;
    }
    __syncthreads();
    bf16x8 af[4], bfr[4];
#pragma unroll
    for (int i = 0; i < 4; ++i)
      af[i] = __builtin_bit_cast(bf16x8, *(const u32x4*)(As + (wm + i * 16 + r16) * LDT + quad * 8));
#pragma unroll
    for (int j = 0; j < 4; ++j)
      bfr[j] = __builtin_bit_cast(bf16x8, *(const u32x4*)(Bs + (wn + j * 16 + r16) * LDT + quad * 8));
#pragma unroll
    for (int i = 0; i < 4; ++i)
#pragma unroll
      for (int j = 0; j < 4; ++j)
        acc[i][j] = __builtin_amdgcn_mfma_f32_16x16x32_bf16(af[i], bfr[j], acc[i][j], 0, 0, 0);
    __syncthreads();
  }

#pragma unroll
  for (int j = 0; j < 4; ++j) {
    const int n = n0 + wn + j * 16 + r16;
    const float bv = bias[n];
#pragma unroll
    for (int i = 0; i < 4; ++i) {
      const int mr = m0 + wm + i * 16 + quad * 4;
#pragma unroll
      for (int r = 0; r < 4; ++r) {
        float v = acc[i][j][r] + bv;
        if constexpr (OUT_BF16)
          ((unsigned short*)Cout)[(size_t)(mr + r) * N + n] = f2bf(v);
        else
          ((float*)Cout)[(size_t)(mr + r) * N + n] = v;
      }
    }
  }
}

// --------------- flash attention, causal, muP scale 1/128 ---------------
// Block = 4 independent waves; wave owns 16 q-rows. kv tiles of 64.
// No __syncthreads: P LDS region is wave-private.
__global__ __launch_bounds__(256) void attn_kernel(const unsigned short* __restrict__ qkv,
                                                   const unsigned short* __restrict__ vT,
                                                   unsigned short* __restrict__ y) {
  __shared__ unsigned short plds[4 * 16 * 72];
  const int tid  = threadIdx.x;
  const int lane = tid & 63;
  const int wave = tid >> 6;
  const int r16  = lane & 15;
  const int quad = lane >> 4;
  const int q0 = blockIdx.x * 64;
  const int bh = blockIdx.y;
  const int b = bh >> 4, h = bh & 15;
  const int qrow = q0 + wave * 16;
  unsigned short* pl = plds + wave * 16 * 72;

  // Q fragments (A-layout): Q[m=r16][k=kc*32+quad*8+j]
  bf16x8 aq[4];
  {
    const unsigned short* qp = qkv + (size_t)(b * 2048 + qrow + r16) * 6144 + h * 128;
#pragma unroll
    for (int kc = 0; kc < 4; ++kc)
      aq[kc] = __builtin_bit_cast(bf16x8, *(const u32x4*)(qp + kc * 32 + quad * 8));
  }

  f32x4 o[8] = {};
  float m_r[4], l_r[4];
#pragma unroll
  for (int r = 0; r < 4; ++r) { m_r[r] = -1e30f; l_r[r] = 0.0f; }
  const int myq = qrow + quad * 4;  // +r gives this lane's C-row

  for (int kv0 = 0; kv0 <= q0; kv0 += 64) {
    // S = Q K^T : B-frag = K[kv=r16][d=kc*32+quad*8+j], direct from global
    f32x4 s[4] = {};
    const unsigned short* kp = qkv + (size_t)(b * 2048 + kv0 + r16) * 6144 + 2048 + h * 128;
#pragma unroll
    for (int nt = 0; nt < 4; ++nt) {
#pragma unroll
      for (int kc = 0; kc < 4; ++kc) {
        bf16x8 bk = __builtin_bit_cast(bf16x8,
            *(const u32x4*)(kp + (size_t)nt * 16 * 6144 + kc * 32 + quad * 8));
        s[nt] = __builtin_amdgcn_mfma_f32_16x16x32_bf16(aq[kc], bk, s[nt], 0, 0, 0);
      }
    }
    // scale + causal mask + online softmax (row reduce across 16 lanes of quad)
#pragma unroll
    for (int r = 0; r < 4; ++r) {
      const int qg = myq + r;
      float sv[4];
      float rowmax = -1e30f;
#pragma unroll
      for (int nt = 0; nt < 4; ++nt) {
        float xel = s[nt][r] * 0.0078125f;            // 1/128 muP scale
        if (kv0 + nt * 16 + r16 > qg) xel = -1e30f;   // causal
        sv[nt] = xel;
        rowmax = fmaxf(rowmax, xel);
      }
#pragma unroll
      for (int off = 8; off >= 1; off >>= 1)
        rowmax = fmaxf(rowmax, __shfl_xor(rowmax, off));
      const float mnew  = fmaxf(m_r[r], rowmax);
      const float alpha = exp2f((m_r[r] - mnew) * 1.44269504f);
      float rs = 0.0f;
#pragma unroll
      for (int nt = 0; nt < 4; ++nt) {
        float p = exp2f((sv[nt] - mnew) * 1.44269504f);
        rs += p;
        pl[(quad * 4 + r) * 72 + nt * 16 + r16] = f2bf(p);  // C-layout -> LDS
      }
#pragma unroll
      for (int off = 8; off >= 1; off >>= 1)
        rs += __shfl_xor(rs, off);
      l_r[r] = l_r[r] * alpha + rs;
      m_r[r] = mnew;
#pragma unroll
      for (int d = 0; d < 8; ++d) o[d][r] *= alpha;
    }
    // P (A-layout from LDS) @ V (B-frag from vT, contiguous in kv)
    bf16x8 ap[2];
#pragma unroll
    for (int kc = 0; kc < 2; ++kc)
      ap[kc] = __builtin_bit_cast(bf16x8, *(const u32x4*)(pl + r16 * 72 + kc * 32 + quad * 8));
    const unsigned short* vp = vT + ((size_t)bh * 128 + r16) * 2048 + kv0;
#pragma unroll
    for (int d = 0; d < 8; ++d) {
#pragma unroll
      for (int kc = 0; kc < 2; ++kc) {
        bf16x8 bv = __builtin_bit_cast(bf16x8,
            *(const u32x4*)(vp + (size_t)d * 16 * 2048 + kc * 32 + quad * 8));
        o[d] = __builtin_amdgcn_mfma_f32_16x16x32_bf16(ap[kc], bv, o[d], 0, 0, 0);
      }
    }
  }
  // normalize + write y[b*2048+q][h*128+d] bf16
#pragma unroll
  for (int r = 0; r < 4; ++r) {
    const float inv = 1.0f / l_r[r];
    unsigned short* yp = y + (size_t)(b * 2048 + myq + r) * 2048 + h * 128;
#pragma unroll
    for (int d = 0; d < 8; ++d)
      yp[d * 16 + r16] = f2bf(o[d][r] * inv);
  }
}

extern "C" void kernel_launch(void* const* d_in, const int* in_sizes, int n_in,
                              void* d_out, int out_size, void* d_ws, size_t ws_size,
                              hipStream_t stream) {
  const float* x     = (const float*)d_in[0];
  const float* W_qkv = (const float*)d_in[1];
  const float* b_qkv = (const float*)d_in[2];
  const float* W_out = (const float*)d_in[3];
  const float* b_out = (const float*)d_in[4];

  unsigned short* ws  = (unsigned short*)d_ws;
  unsigned short* qkv = ws;                   // 50,331,648
  unsigned short* vT  = ws + 50331648;        // 16,777,216
  unsigned short* xb  = ws + 67108864;        // 16,777,216 (y overlays xb)
  unsigned short* wqT = ws + 83886080;        // 12,582,912
  unsigned short* woT = ws + 96468992;        //  4,194,304
  unsigned short* y   = xb;

  cast_x_kernel<<<8192, 256, 0, stream>>>(x, xb);
  transpose_cast_w<<<dim3(32, 96), 256, 0, stream>>>(W_qkv, wqT, 2048, 6144);
  transpose_cast_w<<<dim3(32, 32), 256, 0, stream>>>(W_out, woT, 2048, 2048);
  gemm_bt<true><<<dim3(64, 48), 256, 0, stream>>>(xb, wqT, b_qkv, qkv, 8192, 6144, 2048);
  transpose_v_kernel<<<dim3(32, 2, 64), 256, 0, stream>>>(qkv, vT);
  attn_kernel<<<dim3(32, 64), 256, 0, stream>>>(qkv, vT, y);
  gemm_bt<false><<<dim3(64, 16), 256, 0, stream>>>(y, woT, b_out, d_out, 8192, 2048, 2048);
}

// Round 2
// 784.995 us; speedup vs baseline: 1.9648x; 1.9648x over previous
//
#include <hip/hip_runtime.h>
#include <hip/hip_bf16.h>
#include <cstdint>

// MupCausalSelfAttention on MI355X (gfx950), bf16 MFMA pipeline.
// B=4, T=2048, C=2048, H=16, Dh=128. muP scale = 1/Dh = 1/128.
//
// ws layout (bf16 elems):
//   qkv  : [8192][6144]                 50,331,648 elems
//   vT   : [64 bh][128 d][2048 t]       16,777,216
//   xb/y : [8192][2048] (y overlays xb) 16,777,216
//   wqT  : [6144][2048]                 12,582,912
//   woT  : [2048][2048]                  4,194,304
//   total 100,663,296 elems = 201,326,592 bytes of d_ws.

using f32x4  = __attribute__((ext_vector_type(4))) float;
using u32x4  = __attribute__((ext_vector_type(4))) unsigned int;
using u16x8  = __attribute__((ext_vector_type(8))) unsigned short;
using u16x4  = __attribute__((ext_vector_type(4))) unsigned short;
using bf16x8 = __attribute__((ext_vector_type(8))) __bf16;

__device__ __forceinline__ unsigned short f2bf(float f) {
  unsigned int u = __builtin_bit_cast(unsigned int, f);
  u += 0x7fffu + ((u >> 16) & 1u);   // round-to-nearest-even
  return (unsigned short)(u >> 16);
}

// async 16B global->LDS DMA (dest must be wave-uniform base + lane*16)
__device__ __forceinline__ void async_copy16(const unsigned short* g, unsigned short* l) {
  __builtin_amdgcn_global_load_lds(
      (const __attribute__((address_space(1))) unsigned int*)g,
      (__attribute__((address_space(3))) unsigned int*)l,
      16, 0, 0);
}

// ---------------- cast x fp32 -> bf16, 8 elems/thread ----------------
__global__ __launch_bounds__(256) void cast_x_kernel(const float* __restrict__ x,
                                                     unsigned short* __restrict__ xb) {
  const size_t i = (size_t)blockIdx.x * 256 + threadIdx.x;
  const float* p = x + i * 8;
  f32x4 a = *(const f32x4*)p;
  f32x4 b = *(const f32x4*)(p + 4);
  u16x8 o;
#pragma unroll
  for (int e = 0; e < 4; ++e) { o[e] = f2bf(a[e]); o[e + 4] = f2bf(b[e]); }
  *(u32x4*)(xb + i * 8) = __builtin_bit_cast(u32x4, o);
}

// ---------- W[K][N] fp32 -> WT[N][K] bf16, 64x64 LDS tile ----------
__global__ __launch_bounds__(256) void transpose_cast_w(const float* __restrict__ W,
                                                        unsigned short* __restrict__ WT,
                                                        int K, int N) {
  __shared__ unsigned short tbuf[64 * 68];
  const int tid = threadIdx.x;
  const int k0 = blockIdx.x * 64, n0 = blockIdx.y * 64;
#pragma unroll
  for (int it = 0; it < 4; ++it) {
    int c = it * 256 + tid;
    int kl = c >> 4, n4 = (c & 15) * 4;
    f32x4 v = *(const f32x4*)(W + (size_t)(k0 + kl) * N + n0 + n4);
#pragma unroll
    for (int e = 0; e < 4; ++e) tbuf[(n4 + e) * 68 + kl] = f2bf(v[e]);
  }
  __syncthreads();
#pragma unroll
  for (int it = 0; it < 2; ++it) {
    int c = it * 256 + tid;
    int nl = c >> 3, k8 = (c & 7) * 8;
    u16x4 lo = *(const u16x4*)&tbuf[nl * 68 + k8];
    u16x4 hi = *(const u16x4*)&tbuf[nl * 68 + k8 + 4];
    u16x8 o;
#pragma unroll
    for (int e = 0; e < 4; ++e) { o[e] = lo[e]; o[e + 4] = hi[e]; }
    *(u32x4*)(WT + (size_t)(n0 + nl) * K + k0 + k8) = __builtin_bit_cast(u32x4, o);
  }
}

// ---- qkv V-slice -> vT[bh][128 d][2048 t] bf16, 64x64 LDS tile ----
__global__ __launch_bounds__(256) void transpose_v_kernel(const unsigned short* __restrict__ qkv,
                                                          unsigned short* __restrict__ vT) {
  __shared__ unsigned short tbuf[64 * 68];
  const int tid = threadIdx.x;
  const int t0 = blockIdx.x * 64;
  const int d0 = blockIdx.y * 64;
  const int bh = blockIdx.z;
  const int b = bh >> 4, h = bh & 15;
#pragma unroll
  for (int it = 0; it < 2; ++it) {
    int c = it * 256 + tid;
    int tl = c >> 3, d8 = (c & 7) * 8;
    u32x4 v = *(const u32x4*)(qkv + (size_t)(b * 2048 + t0 + tl) * 6144 + 4096 + h * 128 + d0 + d8);
    u16x8 u = __builtin_bit_cast(u16x8, v);
#pragma unroll
    for (int e = 0; e < 8; ++e) tbuf[(d8 + e) * 68 + tl] = u[e];
  }
  __syncthreads();
#pragma unroll
  for (int it = 0; it < 2; ++it) {
    int c = it * 256 + tid;
    int dl = c >> 3, t8 = (c & 7) * 8;
    u16x4 lo = *(const u16x4*)&tbuf[dl * 68 + t8];
    u16x4 hi = *(const u16x4*)&tbuf[dl * 68 + t8 + 4];
    u16x8 o;
#pragma unroll
    for (int e = 0; e < 4; ++e) { o[e] = lo[e]; o[e + 4] = hi[e]; }
    *(u32x4*)(vT + ((size_t)bh * 128 + d0 + dl) * 2048 + t0 + t8) = __builtin_bit_cast(u32x4, o);
  }
}

// ------- C[M,N] = A[M,K] @ BT[N,K]^T + bias, bf16 MFMA 16x16x32 -------
template <bool OUT_BF16>
__global__ __launch_bounds__(256) void gemm_bt(const unsigned short* __restrict__ A,
                                               const unsigned short* __restrict__ BT,
                                               const float* __restrict__ bias,
                                               void* __restrict__ Cout,
                                               int M, int N, int K) {
  constexpr int LDT = 40;
  __shared__ unsigned short As[128 * LDT];
  __shared__ unsigned short Bs[128 * LDT];
  const int tid  = threadIdx.x;
  const int lane = tid & 63;
  const int wave = tid >> 6;
  const int wm = (wave >> 1) * 64;
  const int wn = (wave & 1) * 64;
  const int m0 = blockIdx.x * 128;
  const int n0 = blockIdx.y * 128;
  const int r16  = lane & 15;
  const int quad = lane >> 4;
  const int sr = tid >> 2;
  const int sc = (tid & 3) * 8;

  f32x4 acc[4][4] = {};
  const unsigned short* Aptr = A + (size_t)(m0 + sr) * K + sc;
  const unsigned short* Bptr = BT + (size_t)(n0 + sr) * K + sc;

  for (int k0 = 0; k0 < K; k0 += 32) {
#pragma unroll
    for (int half = 0; half < 2; ++half) {
      u32x4 va = *(const u32x4*)(Aptr + (size_t)half * 64 * K + k0);
      u32x4 vb = *(const u32x4*)(Bptr + (size_t)half * 64 * K + k0);
      *(u32x4*)(As + (sr + half * 64) * LDT + sc) = va;
      *(u32x4*)(Bs + (sr + half * 64) * LDT + sc) = vb;
    }
    __syncthreads();
    bf16x8 af[4], bfr[4];
#pragma unroll
    for (int i = 0; i < 4; ++i)
      af[i] = __builtin_bit_cast(bf16x8, *(const u32x4*)(As + (wm + i * 16 + r16) * LDT + quad * 8));
#pragma unroll
    for (int j = 0; j < 4; ++j)
      bfr[j] = __builtin_bit_cast(bf16x8, *(const u32x4*)(Bs + (wn + j * 16 + r16) * LDT + quad * 8));
#pragma unroll
    for (int i = 0; i < 4; ++i)
#pragma unroll
      for (int j = 0; j < 4; ++j)
        acc[i][j] = __builtin_amdgcn_mfma_f32_16x16x32_bf16(af[i], bfr[j], acc[i][j], 0, 0, 0);
    __syncthreads();
  }

#pragma unroll
  for (int j = 0; j < 4; ++j) {
    const int n = n0 + wn + j * 16 + r16;
    const float bv = bias[n];
#pragma unroll
    for (int i = 0; i < 4; ++i) {
      const int mr = m0 + wm + i * 16 + quad * 4;
#pragma unroll
      for (int r = 0; r < 4; ++r) {
        float v = acc[i][j][r] + bv;
        if constexpr (OUT_BF16)
          ((unsigned short*)Cout)[(size_t)(mr + r) * N + n] = f2bf(v);
        else
          ((float*)Cout)[(size_t)(mr + r) * N + n] = v;
      }
    }
  }
}

// --------------- flash attention v2, causal, muP scale 1/128 ---------------
// Block = 4 waves, 128 q-rows (32/wave as 2 m-tiles). kv tiles of 64 staged
// in LDS via global_load_lds(16B) with XOR chunk swizzle (no padding allowed,
// swizzle keeps ds_read_b128 frags at <=2-way bank aliasing).
// No online max: muP scale 1/128 keeps logits O(1); softmax shift-invariant.
__global__ __launch_bounds__(256) void attn_kernel(const unsigned short* __restrict__ qkv,
                                                   const unsigned short* __restrict__ vT,
                                                   unsigned short* __restrict__ y) {
  __shared__ unsigned short Ks[64 * 128];    // [kvrow][chunk c]: holds K chunk c^(row&15)
  __shared__ unsigned short Vs[128 * 64];    // [drow][chunk c]: holds vT chunk c^(drow&7)
  __shared__ unsigned short Ps[4][32 * 72];  // per-wave P (C-layout -> A-layout bridge)

  const int tid  = threadIdx.x;
  const int lane = tid & 63;
  const int wave = tid >> 6;
  const int r16  = lane & 15;
  const int quad = lane >> 4;
  const int qt   = 15 - blockIdx.x;          // heavy (large-q) blocks first
  const int q0   = qt * 128;
  const int bh   = blockIdx.y;
  const int b    = bh >> 4, h = bh & 15;
  const int wq0  = q0 + wave * 32;
  unsigned short* pl = Ps[wave];

  // Q A-frags: Q[m=r16][k=kc*32+quad*8+j]
  bf16x8 aq[2][4];
#pragma unroll
  for (int mi = 0; mi < 2; ++mi) {
    const unsigned short* qp = qkv + (size_t)(b * 2048 + wq0 + mi * 16 + r16) * 6144 + h * 128;
#pragma unroll
    for (int kc = 0; kc < 4; ++kc)
      aq[mi][kc] = __builtin_bit_cast(bf16x8, *(const u32x4*)(qp + kc * 32 + quad * 8));
  }

  f32x4 o[2][8] = {};
  float rs_l[2][4] = {};

  const unsigned short* kbase = qkv + (size_t)b * 2048 * 6144 + 2048 + h * 128;
  const unsigned short* vbase = vT + (size_t)bh * 128 * 2048;
  const int ntiles = 2 * qt + 2;

  for (int t = 0; t < ntiles; ++t) {
    const int kv0 = t * 64;
    // stage K tile: 64 rows x 16 chunks(16B); slot(row,c) <- K chunk c^(row&15)
#pragma unroll
    for (int it = 0; it < 4; ++it) {
      const int slot = it * 256 + tid;
      const int row = slot >> 4, c = slot & 15;
      const int g = c ^ (row & 15);
      async_copy16(kbase + (size_t)(kv0 + row) * 6144 + g * 8, Ks + slot * 8);
    }
    // stage V tile: 128 d-rows x 8 chunks; slot(dr,c) <- vT chunk c^(dr&7)
#pragma unroll
    for (int it = 0; it < 4; ++it) {
      const int slot = it * 256 + tid;
      const int dr = slot >> 3, c = slot & 7;
      const int g = c ^ (dr & 7);
      async_copy16(vbase + (size_t)dr * 2048 + kv0 + g * 8, Vs + slot * 8);
    }
    __syncthreads();

    // S = Q K^T  (B-frag: K[kv=n][d=k], swizzled read from Ks)
    f32x4 s[2][4] = {};
#pragma unroll
    for (int kc = 0; kc < 4; ++kc) {
#pragma unroll
      for (int nt = 0; nt < 4; ++nt) {
        const int krow = nt * 16 + r16;
        const int chunk = kc * 4 + quad;
        bf16x8 bk = __builtin_bit_cast(bf16x8,
            *(const u32x4*)(Ks + (krow * 16 + (chunk ^ (krow & 15))) * 8));
#pragma unroll
        for (int mi = 0; mi < 2; ++mi)
          s[mi][nt] = __builtin_amdgcn_mfma_f32_16x16x32_bf16(aq[mi][kc], bk, s[mi][nt], 0, 0, 0);
      }
    }

    const bool need_mask = (kv0 + 64 > wq0);  // wave-uniform
#pragma unroll
    for (int mi = 0; mi < 2; ++mi) {
#pragma unroll
      for (int r = 0; r < 4; ++r) {
        const int qg = wq0 + mi * 16 + quad * 4 + r;
        float acc = 0.0f;
#pragma unroll
        for (int nt = 0; nt < 4; ++nt) {
          float e = exp2f(s[mi][nt][r] * 0.0112718764f);  // (1/128)*log2(e)
          if (need_mask && (kv0 + nt * 16 + r16 > qg)) e = 0.0f;
          acc += e;
          pl[(mi * 16 + quad * 4 + r) * 72 + nt * 16 + r16] = f2bf(e);
        }
        rs_l[mi][r] += acc;
      }
    }

    // O += P V  (A-frag from Ps, B-frag: vT[d=n][kv=k] swizzled from Vs)
#pragma unroll
    for (int kc = 0; kc < 2; ++kc) {
      bf16x8 ap[2];
#pragma unroll
      for (int mi = 0; mi < 2; ++mi)
        ap[mi] = __builtin_bit_cast(bf16x8,
            *(const u32x4*)(pl + (mi * 16 + r16) * 72 + kc * 32 + quad * 8));
#pragma unroll
      for (int d = 0; d < 8; ++d) {
        const int drow = d * 16 + r16;
        const int chunk = kc * 4 + quad;
        bf16x8 bv = __builtin_bit_cast(bf16x8,
            *(const u32x4*)(Vs + (drow * 8 + (chunk ^ (drow & 7))) * 8));
#pragma unroll
        for (int mi = 0; mi < 2; ++mi)
          o[mi][d] = __builtin_amdgcn_mfma_f32_16x16x32_bf16(ap[mi], bv, o[mi][d], 0, 0, 0);
      }
    }
    __syncthreads();
  }

  // finalize: one l-reduction at the end, then normalize + store
#pragma unroll
  for (int mi = 0; mi < 2; ++mi) {
#pragma unroll
    for (int r = 0; r < 4; ++r) {
      float rs = rs_l[mi][r];
#pragma unroll
      for (int off = 8; off >= 1; off >>= 1) rs += __shfl_xor(rs, off);
      const float inv = 1.0f / rs;
      const int qg = wq0 + mi * 16 + quad * 4 + r;
      unsigned short* yp = y + (size_t)(b * 2048 + qg) * 2048 + h * 128;
#pragma unroll
      for (int d = 0; d < 8; ++d)
        yp[d * 16 + r16] = f2bf(o[mi][d][r] * inv);
    }
  }
}

extern "C" void kernel_launch(void* const* d_in, const int* in_sizes, int n_in,
                              void* d_out, int out_size, void* d_ws, size_t ws_size,
                              hipStream_t stream) {
  const float* x     = (const float*)d_in[0];
  const float* W_qkv = (const float*)d_in[1];
  const float* b_qkv = (const float*)d_in[2];
  const float* W_out = (const float*)d_in[3];
  const float* b_out = (const float*)d_in[4];

  unsigned short* ws  = (unsigned short*)d_ws;
  unsigned short* qkv = ws;                   // 50,331,648
  unsigned short* vT  = ws + 50331648;        // 16,777,216
  unsigned short* xb  = ws + 67108864;        // 16,777,216 (y overlays xb)
  unsigned short* wqT = ws + 83886080;        // 12,582,912
  unsigned short* woT = ws + 96468992;        //  4,194,304
  unsigned short* y   = xb;

  cast_x_kernel<<<8192, 256, 0, stream>>>(x, xb);
  transpose_cast_w<<<dim3(32, 96), 256, 0, stream>>>(W_qkv, wqT, 2048, 6144);
  transpose_cast_w<<<dim3(32, 32), 256, 0, stream>>>(W_out, woT, 2048, 2048);
  gemm_bt<true><<<dim3(64, 48), 256, 0, stream>>>(xb, wqT, b_qkv, qkv, 8192, 6144, 2048);
  transpose_v_kernel<<<dim3(32, 2, 64), 256, 0, stream>>>(qkv, vT);
  attn_kernel<<<dim3(16, 64), 256, 0, stream>>>(qkv, vT, y);
  gemm_bt<false><<<dim3(64, 16), 256, 0, stream>>>(y, woT, b_out, d_out, 8192, 2048, 2048);
}

// Round 3
// 774.594 us; speedup vs baseline: 1.9912x; 1.0134x over previous
//
#include <hip/hip_runtime.h>
#include <hip/hip_bf16.h>
#include <cstdint>

// MupCausalSelfAttention on MI355X (gfx950), bf16 MFMA pipeline.
// B=4, T=2048, C=2048, H=16, Dh=128. muP scale = 1/Dh = 1/128.
//
// ws layout (bf16 elems):
//   qkv  : [8192][6144]                 50,331,648 elems
//   vT   : [64 bh][128 d][2048 t]       16,777,216
//   xb/y : [8192][2048] (y overlays xb) 16,777,216
//   wqT  : [6144][2048]                 12,582,912
//   woT  : [2048][2048]                  4,194,304
//   total 100,663,296 elems = 201,326,592 bytes of d_ws.

using f32x4  = __attribute__((ext_vector_type(4))) float;
using u32x4  = __attribute__((ext_vector_type(4))) unsigned int;
using u16x8  = __attribute__((ext_vector_type(8))) unsigned short;
using u16x4  = __attribute__((ext_vector_type(4))) unsigned short;
using bf16x8 = __attribute__((ext_vector_type(8))) __bf16;

__device__ __forceinline__ unsigned short f2bf(float f) {
  unsigned int u = __builtin_bit_cast(unsigned int, f);
  u += 0x7fffu + ((u >> 16) & 1u);   // round-to-nearest-even
  return (unsigned short)(u >> 16);
}

// async 16B global->LDS DMA (dest is wave-uniform base + lane*16)
__device__ __forceinline__ void async_copy16(const unsigned short* g, unsigned short* l) {
  __builtin_amdgcn_global_load_lds(
      (const __attribute__((address_space(1))) unsigned int*)g,
      (__attribute__((address_space(3))) unsigned int*)l,
      16, 0, 0);
}

// ---------------- cast x fp32 -> bf16, 8 elems/thread ----------------
__global__ __launch_bounds__(256) void cast_x_kernel(const float* __restrict__ x,
                                                     unsigned short* __restrict__ xb) {
  const size_t i = (size_t)blockIdx.x * 256 + threadIdx.x;
  const float* p = x + i * 8;
  f32x4 a = *(const f32x4*)p;
  f32x4 b = *(const f32x4*)(p + 4);
  u16x8 o;
#pragma unroll
  for (int e = 0; e < 4; ++e) { o[e] = f2bf(a[e]); o[e + 4] = f2bf(b[e]); }
  *(u32x4*)(xb + i * 8) = __builtin_bit_cast(u32x4, o);
}

// ---------- W[K][N] fp32 -> WT[N][K] bf16, 64x64 LDS tile ----------
__global__ __launch_bounds__(256) void transpose_cast_w(const float* __restrict__ W,
                                                        unsigned short* __restrict__ WT,
                                                        int K, int N) {
  __shared__ unsigned short tbuf[64 * 68];
  const int tid = threadIdx.x;
  const int k0 = blockIdx.x * 64, n0 = blockIdx.y * 64;
#pragma unroll
  for (int it = 0; it < 4; ++it) {
    int c = it * 256 + tid;
    int kl = c >> 4, n4 = (c & 15) * 4;
    f32x4 v = *(const f32x4*)(W + (size_t)(k0 + kl) * N + n0 + n4);
#pragma unroll
    for (int e = 0; e < 4; ++e) tbuf[(n4 + e) * 68 + kl] = f2bf(v[e]);
  }
  __syncthreads();
#pragma unroll
  for (int it = 0; it < 2; ++it) {
    int c = it * 256 + tid;
    int nl = c >> 3, k8 = (c & 7) * 8;
    u16x4 lo = *(const u16x4*)&tbuf[nl * 68 + k8];
    u16x4 hi = *(const u16x4*)&tbuf[nl * 68 + k8 + 4];
    u16x8 o;
#pragma unroll
    for (int e = 0; e < 4; ++e) { o[e] = lo[e]; o[e + 4] = hi[e]; }
    *(u32x4*)(WT + (size_t)(n0 + nl) * K + k0 + k8) = __builtin_bit_cast(u32x4, o);
  }
}

// ---- qkv V-slice -> vT[bh][128 d][2048 t] bf16, 64x64 LDS tile ----
__global__ __launch_bounds__(256) void transpose_v_kernel(const unsigned short* __restrict__ qkv,
                                                          unsigned short* __restrict__ vT) {
  __shared__ unsigned short tbuf[64 * 68];
  const int tid = threadIdx.x;
  const int t0 = blockIdx.x * 64;
  const int d0 = blockIdx.y * 64;
  const int bh = blockIdx.z;
  const int b = bh >> 4, h = bh & 15;
#pragma unroll
  for (int it = 0; it < 2; ++it) {
    int c = it * 256 + tid;
    int tl = c >> 3, d8 = (c & 7) * 8;
    u32x4 v = *(const u32x4*)(qkv + (size_t)(b * 2048 + t0 + tl) * 6144 + 4096 + h * 128 + d0 + d8);
    u16x8 u = __builtin_bit_cast(u16x8, v);
#pragma unroll
    for (int e = 0; e < 8; ++e) tbuf[(d8 + e) * 68 + tl] = u[e];
  }
  __syncthreads();
#pragma unroll
  for (int it = 0; it < 2; ++it) {
    int c = it * 256 + tid;
    int dl = c >> 3, t8 = (c & 7) * 8;
    u16x4 lo = *(const u16x4*)&tbuf[dl * 68 + t8];
    u16x4 hi = *(const u16x4*)&tbuf[dl * 68 + t8 + 4];
    u16x8 o;
#pragma unroll
    for (int e = 0; e < 4; ++e) { o[e] = lo[e]; o[e + 4] = hi[e]; }
    *(u32x4*)(vT + ((size_t)bh * 128 + d0 + dl) * 2048 + t0 + t8) = __builtin_bit_cast(u32x4, o);
  }
}

// ------- C[M,N] = A[M,K] @ BT[N,K]^T + bias, bf16 MFMA 16x16x32 -------
// m97 structure: global_load_lds(16B) staging, unpadded LDS, single-buffered.
// XOR chunk swizzle slot(row,c) <- chunk c^((row>>1)&3): every b128 fragment
// read is exactly 2-way on banks (free, m136). Fragment-side swizzle reduces
// to quad^((r16>>1)&3), i-independent.
template <bool OUT_BF16>
__global__ __launch_bounds__(256) void gemm_bt(const unsigned short* __restrict__ A,
                                               const unsigned short* __restrict__ BT,
                                               const float* __restrict__ bias,
                                               void* __restrict__ Cout,
                                               int M, int N, int K) {
  __shared__ unsigned short As[128 * 32];
  __shared__ unsigned short Bs[128 * 32];
  const int tid  = threadIdx.x;
  const int lane = tid & 63;
  const int wave = tid >> 6;
  const int wm = (wave >> 1) * 64;
  const int wn = (wave & 1) * 64;
  const int m0 = blockIdx.x * 128;
  const int n0 = blockIdx.y * 128;
  const int r16  = lane & 15;
  const int quad = lane >> 4;
  const int sw   = quad ^ ((r16 >> 1) & 3);  // fragment chunk swizzle

  // staging: slot = it*256+tid; row=slot>>2, c=slot&3, src chunk g=c^((row>>1)&3)
  const int srow0 = tid >> 2;
  const int g0 = (tid & 3) ^ ((tid >> 3) & 3);

  f32x4 acc[4][4] = {};
  const unsigned short* Ab = A + (size_t)m0 * K;
  const unsigned short* Bb = BT + (size_t)n0 * K;

  for (int k0 = 0; k0 < K; k0 += 32) {
#pragma unroll
    for (int it = 0; it < 2; ++it) {
      const int row = it * 64 + srow0;
      async_copy16(Ab + (size_t)row * K + k0 + g0 * 8, As + (it * 256 + tid) * 8);
      async_copy16(Bb + (size_t)row * K + k0 + g0 * 8, Bs + (it * 256 + tid) * 8);
    }
    __syncthreads();
    bf16x8 af[4], bfr[4];
#pragma unroll
    for (int i = 0; i < 4; ++i)
      af[i] = __builtin_bit_cast(bf16x8,
          *(const u32x4*)(As + ((wm + i * 16 + r16) * 4 + sw) * 8));
#pragma unroll
    for (int j = 0; j < 4; ++j)
      bfr[j] = __builtin_bit_cast(bf16x8,
          *(const u32x4*)(Bs + ((wn + j * 16 + r16) * 4 + sw) * 8));
#pragma unroll
    for (int i = 0; i < 4; ++i)
#pragma unroll
      for (int j = 0; j < 4; ++j)
        acc[i][j] = __builtin_amdgcn_mfma_f32_16x16x32_bf16(af[i], bfr[j], acc[i][j], 0, 0, 0);
    __syncthreads();
  }

#pragma unroll
  for (int j = 0; j < 4; ++j) {
    const int n = n0 + wn + j * 16 + r16;
    const float bv = bias[n];
#pragma unroll
    for (int i = 0; i < 4; ++i) {
      const int mr = m0 + wm + i * 16 + quad * 4;
#pragma unroll
      for (int r = 0; r < 4; ++r) {
        float v = acc[i][j][r] + bv;
        if constexpr (OUT_BF16)
          ((unsigned short*)Cout)[(size_t)(mr + r) * N + n] = f2bf(v);
        else
          ((float*)Cout)[(size_t)(mr + r) * N + n] = v;
      }
    }
  }
}

// --------------- flash attention v2, causal, muP scale 1/128 ---------------
// Block = 4 waves, 128 q-rows (32/wave as 2 m-tiles). kv tiles of 64 staged
// in LDS via global_load_lds(16B) with XOR chunk swizzle.
// No online max: muP scale 1/128 keeps logits O(1); softmax shift-invariant.
__global__ __launch_bounds__(256) void attn_kernel(const unsigned short* __restrict__ qkv,
                                                   const unsigned short* __restrict__ vT,
                                                   unsigned short* __restrict__ y) {
  __shared__ unsigned short Ks[64 * 128];    // [kvrow][chunk c]: holds K chunk c^(row&15)
  __shared__ unsigned short Vs[128 * 64];    // [drow][chunk c]: holds vT chunk c^(drow&7)
  __shared__ unsigned short Ps[4][32 * 72];  // per-wave P (C-layout -> A-layout bridge)

  const int tid  = threadIdx.x;
  const int lane = tid & 63;
  const int wave = tid >> 6;
  const int r16  = lane & 15;
  const int quad = lane >> 4;
  const int qt   = 15 - blockIdx.x;          // heavy (large-q) blocks first
  const int q0   = qt * 128;
  const int bh   = blockIdx.y;
  const int b    = bh >> 4, h = bh & 15;
  const int wq0  = q0 + wave * 32;
  unsigned short* pl = Ps[wave];

  // Q A-frags: Q[m=r16][k=kc*32+quad*8+j]
  bf16x8 aq[2][4];
#pragma unroll
  for (int mi = 0; mi < 2; ++mi) {
    const unsigned short* qp = qkv + (size_t)(b * 2048 + wq0 + mi * 16 + r16) * 6144 + h * 128;
#pragma unroll
    for (int kc = 0; kc < 4; ++kc)
      aq[mi][kc] = __builtin_bit_cast(bf16x8, *(const u32x4*)(qp + kc * 32 + quad * 8));
  }

  f32x4 o[2][8] = {};
  float rs_l[2][4] = {};

  const unsigned short* kbase = qkv + (size_t)b * 2048 * 6144 + 2048 + h * 128;
  const unsigned short* vbase = vT + (size_t)bh * 128 * 2048;
  const int ntiles = 2 * qt + 2;

  for (int t = 0; t < ntiles; ++t) {
    const int kv0 = t * 64;
    // stage K tile: 64 rows x 16 chunks(16B); slot(row,c) <- K chunk c^(row&15)
#pragma unroll
    for (int it = 0; it < 4; ++it) {
      const int slot = it * 256 + tid;
      const int row = slot >> 4, c = slot & 15;
      const int g = c ^ (row & 15);
      async_copy16(kbase + (size_t)(kv0 + row) * 6144 + g * 8, Ks + slot * 8);
    }
    // stage V tile: 128 d-rows x 8 chunks; slot(dr,c) <- vT chunk c^(dr&7)
#pragma unroll
    for (int it = 0; it < 4; ++it) {
      const int slot = it * 256 + tid;
      const int dr = slot >> 3, c = slot & 7;
      const int g = c ^ (dr & 7);
      async_copy16(vbase + (size_t)dr * 2048 + kv0 + g * 8, Vs + slot * 8);
    }
    __syncthreads();

    // S = Q K^T  (B-frag: K[kv=n][d=k], swizzled read from Ks)
    f32x4 s[2][4] = {};
#pragma unroll
    for (int kc = 0; kc < 4; ++kc) {
#pragma unroll
      for (int nt = 0; nt < 4; ++nt) {
        const int krow = nt * 16 + r16;
        const int chunk = kc * 4 + quad;
        bf16x8 bk = __builtin_bit_cast(bf16x8,
            *(const u32x4*)(Ks + (krow * 16 + (chunk ^ (krow & 15))) * 8));
#pragma unroll
        for (int mi = 0; mi < 2; ++mi)
          s[mi][nt] = __builtin_amdgcn_mfma_f32_16x16x32_bf16(aq[mi][kc], bk, s[mi][nt], 0, 0, 0);
      }
    }

    const bool need_mask = (kv0 + 64 > wq0);  // wave-uniform
#pragma unroll
    for (int mi = 0; mi < 2; ++mi) {
#pragma unroll
      for (int r = 0; r < 4; ++r) {
        const int qg = wq0 + mi * 16 + quad * 4 + r;
        float acc = 0.0f;
#pragma unroll
        for (int nt = 0; nt < 4; ++nt) {
          float e = exp2f(s[mi][nt][r] * 0.0112718764f);  // (1/128)*log2(e)
          if (need_mask && (kv0 + nt * 16 + r16 > qg)) e = 0.0f;
          acc += e;
          pl[(mi * 16 + quad * 4 + r) * 72 + nt * 16 + r16] = f2bf(e);
        }
        rs_l[mi][r] += acc;
      }
    }

    // O += P V  (A-frag from Ps, B-frag: vT[d=n][kv=k] swizzled from Vs)
#pragma unroll
    for (int kc = 0; kc < 2; ++kc) {
      bf16x8 ap[2];
#pragma unroll
      for (int mi = 0; mi < 2; ++mi)
        ap[mi] = __builtin_bit_cast(bf16x8,
            *(const u32x4*)(pl + (mi * 16 + r16) * 72 + kc * 32 + quad * 8));
#pragma unroll
      for (int d = 0; d < 8; ++d) {
        const int drow = d * 16 + r16;
        const int chunk = kc * 4 + quad;
        bf16x8 bv = __builtin_bit_cast(bf16x8,
            *(const u32x4*)(Vs + (drow * 8 + (chunk ^ (drow & 7))) * 8));
#pragma unroll
        for (int mi = 0; mi < 2; ++mi)
          o[mi][d] = __builtin_amdgcn_mfma_f32_16x16x32_bf16(ap[mi], bv, o[mi][d], 0, 0, 0);
      }
    }
    __syncthreads();
  }

  // finalize: one l-reduction at the end, then normalize + store
#pragma unroll
  for (int mi = 0; mi < 2; ++mi) {
#pragma unroll
    for (int r = 0; r < 4; ++r) {
      float rs = rs_l[mi][r];
#pragma unroll
      for (int off = 8; off >= 1; off >>= 1) rs += __shfl_xor(rs, off);
      const float inv = 1.0f / rs;
      const int qg = wq0 + mi * 16 + quad * 4 + r;
      unsigned short* yp = y + (size_t)(b * 2048 + qg) * 2048 + h * 128;
#pragma unroll
      for (int d = 0; d < 8; ++d)
        yp[d * 16 + r16] = f2bf(o[mi][d][r] * inv);
    }
  }
}

extern "C" void kernel_launch(void* const* d_in, const int* in_sizes, int n_in,
                              void* d_out, int out_size, void* d_ws, size_t ws_size,
                              hipStream_t stream) {
  const float* x     = (const float*)d_in[0];
  const float* W_qkv = (const float*)d_in[1];
  const float* b_qkv = (const float*)d_in[2];
  const float* W_out = (const float*)d_in[3];
  const float* b_out = (const float*)d_in[4];

  unsigned short* ws  = (unsigned short*)d_ws;
  unsigned short* qkv = ws;                   // 50,331,648
  unsigned short* vT  = ws + 50331648;        // 16,777,216
  unsigned short* xb  = ws + 67108864;        // 16,777,216 (y overlays xb)
  unsigned short* wqT = ws + 83886080;        // 12,582,912
  unsigned short* woT = ws + 96468992;        //  4,194,304
  unsigned short* y   = xb;

  cast_x_kernel<<<8192, 256, 0, stream>>>(x, xb);
  transpose_cast_w<<<dim3(32, 96), 256, 0, stream>>>(W_qkv, wqT, 2048, 6144);
  transpose_cast_w<<<dim3(32, 32), 256, 0, stream>>>(W_out, woT, 2048, 2048);
  gemm_bt<true><<<dim3(64, 48), 256, 0, stream>>>(xb, wqT, b_qkv, qkv, 8192, 6144, 2048);
  transpose_v_kernel<<<dim3(32, 2, 64), 256, 0, stream>>>(qkv, vT);
  attn_kernel<<<dim3(16, 64), 256, 0, stream>>>(qkv, vT, y);
  gemm_bt<false><<<dim3(64, 16), 256, 0, stream>>>(y, woT, b_out, d_out, 8192, 2048, 2048);
}